// Round 1
// baseline (150.523 us; speedup 1.0000x reference)
//
#include <hip/hip_runtime.h>
#include <math.h>

#define EPSF 1e-8f

__global__ __launch_bounds__(256) void wasserstein_kernel(
    const float* __restrict__ loc1, const float* __restrict__ scale1,
    const float* __restrict__ rot1, const float* __restrict__ loc2,
    const float* __restrict__ scale2, const float* __restrict__ rot2,
    float* __restrict__ out, int B)
{
    int i = blockIdx.x * blockDim.x + threadIdx.x;
    if (i >= B) return;

    const float* l1 = loc1 + 3 * i;
    const float* l2 = loc2 + 3 * i;
    const float* s1p = scale1 + 3 * i;
    const float* s2p = scale2 + 3 * i;
    const float* R1p = rot1 + 9 * i;
    const float* R2p = rot2 + 9 * i;

    float s1[3], s2[3];
#pragma unroll
    for (int k = 0; k < 3; k++) {
        s1[k] = fmaxf(s1p[k], EPSF);
        s2[k] = fmaxf(s2p[k], EPSF);
    }

    float R1[3][3], R2[3][3];
#pragma unroll
    for (int r = 0; r < 3; r++)
#pragma unroll
        for (int c = 0; c < 3; c++) {
            R1[r][c] = R1p[3 * r + c];
            R2[r][c] = R2p[3 * r + c];
        }

    float d0 = l1[0] - l2[0];
    float d1 = l1[1] - l2[1];
    float d2 = l1[2] - l2[2];
    float loc_diff2 = d0 * d0 + d1 * d1 + d2 * d2;

    // cov2[r][c] = sum_j R2[r][j] * s2[j] * R2[c][j]  (symmetric)
    float cov2[3][3];
    float tr_cov2 = 0.0f;
#pragma unroll
    for (int r = 0; r < 3; r++) {
#pragma unroll
        for (int c = r; c < 3; c++) {
            float acc = 0.0f;
#pragma unroll
            for (int j = 0; j < 3; j++)
                acc += R2[r][j] * s2[j] * R2[c][j];
            cov2[r][c] = acc;
            cov2[c][r] = acc;
        }
        tr_cov2 += cov2[r][r];
    }

    // T = cov2 * R1
    float T[3][3];
#pragma unroll
    for (int r = 0; r < 3; r++)
#pragma unroll
        for (int c = 0; c < 3; c++) {
            float acc = 0.0f;
#pragma unroll
            for (int j = 0; j < 3; j++)
                acc += cov2[r][j] * R1[j][c];
            T[r][c] = acc;
        }

    // M = R1^T * T  (cov2 rotated into frame 1)
    float M[3][3];
#pragma unroll
    for (int r = 0; r < 3; r++)
#pragma unroll
        for (int c = 0; c < 3; c++) {
            float acc = 0.0f;
#pragma unroll
            for (int j = 0; j < 3; j++)
                acc += R1[j][r] * T[j][c];
            M[r][c] = acc;
        }

    // E = diag(sqrt(s1)) M diag(sqrt(s1)), symmetrized, + EPS*I
    float ss0 = sqrtf(s1[0]), ss1 = sqrtf(s1[1]), ss2 = sqrtf(s1[2]);
    double a00 = (double)(s1[0] * M[0][0]) + 1e-8;
    double a11 = (double)(s1[1] * M[1][1]) + 1e-8;
    double a22 = (double)(s1[2] * M[2][2]) + 1e-8;
    double a01 = (double)(0.5f * (M[0][1] + M[1][0]) * ss0 * ss1);
    double a02 = (double)(0.5f * (M[0][2] + M[2][0]) * ss0 * ss2);
    double a12 = (double)(0.5f * (M[1][2] + M[2][1]) * ss1 * ss2);

    // Analytic eigenvalues of symmetric 3x3 (trigonometric method), fp64
    double q = (a00 + a11 + a22) * (1.0 / 3.0);
    double b00 = a00 - q, b11 = a11 - q, b22 = a22 - q;
    double p1 = a01 * a01 + a02 * a02 + a12 * a12;
    double p2 = b00 * b00 + b11 * b11 + b22 * b22 + 2.0 * p1;

    double e0, e1, e2;
    if (p2 <= 1e-30) {
        e0 = q; e1 = q; e2 = q;
    } else {
        double p = sqrt(p2 * (1.0 / 6.0));
        double invp = 1.0 / p;
        double c00 = b00 * invp, c11 = b11 * invp, c22 = b22 * invp;
        double c01 = a01 * invp, c02 = a02 * invp, c12 = a12 * invp;
        double detB = c00 * (c11 * c22 - c12 * c12)
                    - c01 * (c01 * c22 - c12 * c02)
                    + c02 * (c01 * c12 - c11 * c02);
        double r = 0.5 * detB;
        r = fmin(1.0, fmax(-1.0, r));
        double phi = acos(r) * (1.0 / 3.0);
        double twop = 2.0 * p;
        e0 = q + twop * cos(phi);
        e2 = q + twop * cos(phi + 2.0943951023931953);  // + 2*pi/3
        e1 = 3.0 * q - e0 - e2;
    }

    double eps_d = 1e-8;
    double tr_sqrt = sqrt(fmax(e0, eps_d)) + sqrt(fmax(e1, eps_d)) + sqrt(fmax(e2, eps_d));

    float cov_w = (s1[0] + s1[1] + s1[2]) + tr_cov2 - 2.0f * (float)tr_sqrt;
    cov_w = fmaxf(cov_w, 0.0f);

    out[i] = sqrtf(fmaxf(loc_diff2 + cov_w, EPSF));
}

extern "C" void kernel_launch(void* const* d_in, const int* in_sizes, int n_in,
                              void* d_out, int out_size, void* d_ws, size_t ws_size,
                              hipStream_t stream) {
    const float* loc1   = (const float*)d_in[0];
    const float* scale1 = (const float*)d_in[1];
    const float* rot1   = (const float*)d_in[2];
    const float* loc2   = (const float*)d_in[3];
    const float* scale2 = (const float*)d_in[4];
    const float* rot2   = (const float*)d_in[5];
    float* out = (float*)d_out;

    int B = in_sizes[0] / 3;
    int block = 256;
    int grid = (B + block - 1) / block;
    wasserstein_kernel<<<grid, block, 0, stream>>>(loc1, scale1, rot1, loc2, scale2, rot2, out, B);
}